// Round 9
// baseline (536.572 us; speedup 1.0000x reference)
//
#include <hip/hip_runtime.h>
#include <hip/hip_cooperative_groups.h>
#include <hip/hip_bf16.h>

namespace cg = cooperative_groups;

// GraphNet2: N=50000 nodes, E=1.6M edges, F=128.
// R1-R8 history: LDS-privatized scatter, j-split encode, transposed replica,
// separate reg-rich head. R8 = 153.5us but interior micro-opts stopped
// paying (-2.4us for a predicted -10): per-kernel time is no longer the
// cost; ~50-60us sits in 3 kernel boundaries (launch + full-device drain).
// R9: ONE cooperative kernel, 256 blocks x 1024 thr, 100KB dynamic LDS
// (1 block/CU, co-resident), grid.sync() between phases:
//   P1 node encode (4x256-thr subs/block, j-split, no spill @ 128 VGPR cap)
//   P2 edge scatter (128 slices x 2 ranges = 256 blocks, LDS table)
//   P3 replica reduce (float4 + xor-shfl) + block softmax partials
//   P4 block 0: merge 782 partials + MLP head (8-way k-split on W2)

#define NF 128
#define DENC 32
#define DEMB 12
#define DH 128

#define NSLICE 128       // edge slices (replica rows)
#define NRANGE 2         // node ranges
#define R_SCAT 25024     // LDS table entries (100096 B dynamic), %64==0
#define ROWB (NSLICE*64) // floats per node-chunk in rep2 (8192)
#define GRID_X (NSLICE*NRANGE)  // 256
#define BLK 1024

struct KArgs {
    const float* nodes; const int* senders; const int* recvs;
    const float* W_enc; const float* b_enc;
    const float* W_inf; const float* b_inf;
    const float* W_emb; const float* b_emb;
    const float* W1; const float* b1;
    const float* W2; const float* b2;
    const float* Wy; const float* by;
    const float* Wx; const float* bx;
    float* p; float* inflb; float* embT; float* rep2; float* psum;
    float* out; int n_nodes; int n_edges;
};

// GEMV over one full node row (k=0..127): acc[j] += x[k]*W[k*LDW+jbase+j].
// jbase wave-uniform -> W/bias loads stay scalar. Returns x[127].
template <int NJ, int LDW>
__device__ __forceinline__ void gemv_rows(
    const float4* __restrict__ x4p, const float* __restrict__ W,
    int jbase, const float* __restrict__ bias, float* acc, float& x_last)
{
#pragma unroll
    for (int j = 0; j < NJ; j++) acc[j] = bias[jbase + j];
#pragma unroll 2
    for (int c = 0; c < 8; c++) {
        float4 xa = x4p[4 * c + 0];
        float4 xb = x4p[4 * c + 1];
        float4 xc = x4p[4 * c + 2];
        float4 xd = x4p[4 * c + 3];
        float xs[16] = {xa.x, xa.y, xa.z, xa.w, xb.x, xb.y, xb.z, xb.w,
                        xc.x, xc.y, xc.z, xc.w, xd.x, xd.y, xd.z, xd.w};
#pragma unroll
        for (int u = 0; u < 16; u++) {
            const int k = 16 * c + u;
#pragma unroll
            for (int j = 0; j < NJ; j++)
                acc[j] = fmaf(xs[u], W[k * LDW + jbase + j], acc[j]);
        }
        if (c == 7) x_last = xd.w;
    }
}

__global__ __launch_bounds__(BLK) void fused(KArgs a)
{
    extern __shared__ float smem[];          // R_SCAT floats (100096 B)
    cg::grid_group grid = cg::this_grid();

    const int tid  = threadIdx.x;
    const int q    = tid >> 8;               // sub-block 0..3 (256 thr each)
    const int lane = tid & 63;
    const int wv   = (tid >> 6) & 3;         // wave within sub
    const int nb64 = (a.n_nodes + 63) >> 6;  // 782

    // ================= Phase 1: node encode (j-split) =================
    {
        float* tabp = smem;                  // [4][3][64]
        const int g    = blockIdx.x * 4 + q; // group 0..1023
        const int node = g * 64 + lane;
        const bool son = (g < nb64);
        const bool ok  = son && (node < a.n_nodes);
        float x127 = 0.f;
        if (son) {
            const float4* x4p = ok ? (const float4*)(a.nodes + (size_t)node * NF)
                                   : (const float4*)a.nodes;
            if (wv == 3) {
                float acc[DEMB];
                gemv_rows<DEMB, DEMB>(x4p, a.W_emb, 0, a.b_emb, acc, x127);
                if (ok) {
#pragma unroll
                    for (int j = 0; j < DEMB; j++)
                        a.embT[(size_t)j * a.n_nodes + node] = acc[j];
                }
            } else {
                const int jbase = __builtin_amdgcn_readfirstlane(wv * 11);
                float pp = 0.f;
                if (wv == 2) {
                    float acc[10];
                    gemv_rows<10, DENC>(x4p, a.W_enc, jbase, a.b_enc, acc, x127);
#pragma unroll
                    for (int j = 0; j < 10; j++)
                        pp += fmaxf(acc[j], 0.f) * a.W_inf[jbase + j];
                } else {
                    float acc[11];
                    gemv_rows<11, DENC>(x4p, a.W_enc, jbase, a.b_enc, acc, x127);
#pragma unroll
                    for (int j = 0; j < 11; j++)
                        pp += fmaxf(acc[j], 0.f) * a.W_inf[jbase + j];
                }
                tabp[(q * 3 + wv) * 64 + lane] = pp;
            }
        }
        __syncthreads();
        if (son && wv == 0 && ok) {
            float pn = tabp[(q * 3 + 0) * 64 + lane]
                     + tabp[(q * 3 + 1) * 64 + lane]
                     + tabp[(q * 3 + 2) * 64 + lane];
            a.p[node] = pn;
            a.inflb[node] = pn + x127 * a.W_inf[DENC] + a.b_inf[0];
        }
    }
    __threadfence();
    grid.sync();

    // ================= Phase 2: LDS edge scatter =================
    {
        float* tab = smem;                   // R_SCAT floats
        const int slice = blockIdx.x >> 1;   // 0..127
        const int rng_i = blockIdx.x & 1;    // 0..1
        const int e0 = (int)((long long)a.n_edges * slice / NSLICE);
        const int e1 = (int)((long long)a.n_edges * (slice + 1) / NSLICE);
        const int lo = rng_i * R_SCAT;
        const int rng = min(R_SCAT, a.n_nodes - lo);

        float4* tab4 = (float4*)tab;
        for (int i = tid; i < (rng + 3) / 4; i += BLK)
            tab4[i] = make_float4(0.f, 0.f, 0.f, 0.f);
        __syncthreads();

        const int ae0 = (e0 + 3) & ~3;
        const int ae1 = e1 & ~3;
        for (int e = e0 + tid; e < ae0; e += BLK) {
            unsigned rr = (unsigned)(a.recvs[e] - lo);
            if (rr < (unsigned)rng) atomicAdd(&tab[rr], a.p[a.senders[e]]);
        }
        const int4* r4 = (const int4*)a.recvs;
        const int4* s4 = (const int4*)a.senders;
        for (int i = ae0 / 4 + tid; i < ae1 / 4; i += BLK) {
            int4 r = r4[i];
            int4 s = s4[i];
            unsigned rr;
            rr = (unsigned)(r.x - lo); if (rr < (unsigned)rng) atomicAdd(&tab[rr], a.p[s.x]);
            rr = (unsigned)(r.y - lo); if (rr < (unsigned)rng) atomicAdd(&tab[rr], a.p[s.y]);
            rr = (unsigned)(r.z - lo); if (rr < (unsigned)rng) atomicAdd(&tab[rr], a.p[s.z]);
            rr = (unsigned)(r.w - lo); if (rr < (unsigned)rng) atomicAdd(&tab[rr], a.p[s.w]);
        }
        for (int e = ae1 + tid; e < e1; e += BLK) {
            unsigned rr = (unsigned)(a.recvs[e] - lo);
            if (rr < (unsigned)rng) atomicAdd(&tab[rr], a.p[a.senders[e]]);
        }
        __syncthreads();

        // writeback: rep2[chunk][slice][col]; lo%64==0
        const int g4base = lo >> 2;
        for (int i4 = tid; i4 < rng / 4; i4 += BLK) {
            const int g4    = g4base + i4;
            const int chunk = g4 >> 4;
            const int col4  = g4 & 15;
            ((float4*)a.rep2)[(size_t)chunk * (ROWB / 4) + slice * 16 + col4] = tab4[i4];
        }
        for (int i = (rng & ~3) + tid; i < rng; i += BLK) {
            const int g = lo + i;
            a.rep2[(size_t)(g >> 6) * ROWB + slice * 64 + (g & 63)] = tab[i];
        }
    }
    __threadfence();
    grid.sync();

    // ======= Phase 3: replica reduce + block softmax partials =======
    {
        float* t3 = smem + q * 256;          // per-sub [4][64]
        const int chunk = blockIdx.x * 4 + q;
        const bool son  = (chunk < nb64);
        const int node  = chunk * 64 + lane;
        const bool ok   = son && (node < a.n_nodes);

        if (son) {
            const float* cb = a.rep2 + (size_t)chunk * ROWB;
            const int s0 = lane >> 4;        // 0..3
            const int c4 = lane & 15;        // 0..15
            float4 ac = make_float4(0.f, 0.f, 0.f, 0.f);
#pragma unroll
            for (int i = 0; i < 8; i++) {
                const int slice = 32 * wv + s0 + 4 * i;
                float4 v = ((const float4*)(cb + slice * 64))[c4];
                ac.x += v.x; ac.y += v.y; ac.z += v.z; ac.w += v.w;
            }
#pragma unroll
            for (int off = 16; off <= 32; off <<= 1) {
                ac.x += __shfl_xor(ac.x, off, 64);
                ac.y += __shfl_xor(ac.y, off, 64);
                ac.z += __shfl_xor(ac.z, off, 64);
                ac.w += __shfl_xor(ac.w, off, 64);
            }
            if (s0 == 0) {
                t3[wv * 64 + 4 * c4 + 0] = ac.x;
                t3[wv * 64 + 4 * c4 + 1] = ac.y;
                t3[wv * 64 + 4 * c4 + 2] = ac.z;
                t3[wv * 64 + 4 * c4 + 3] = ac.w;
            }
        }
        __syncthreads();
        if (son && wv == 0) {
            float infl = ok ? a.inflb[node] + t3[lane] + t3[64 + lane]
                              + t3[128 + lane] + t3[192 + lane]
                            : -1e30f;
            float m = infl;
#pragma unroll
            for (int off = 32; off; off >>= 1)
                m = fmaxf(m, __shfl_down(m, off, 64));
            m = __shfl(m, 0, 64);

            const float w = ok ? expf(infl - m) : 0.f;
            float v13[13];
            v13[0] = w;
#pragma unroll
            for (int j = 0; j < DEMB; j++)
                v13[1 + j] = ok ? w * a.embT[(size_t)j * a.n_nodes + node] : 0.f;
#pragma unroll
            for (int v = 0; v < 13; v++) {
                float x = v13[v];
#pragma unroll
                for (int off = 32; off; off >>= 1)
                    x += __shfl_down(x, off, 64);
                v13[v] = x;
            }
            if (lane == 0) {
                a.psum[chunk * 14] = m;
#pragma unroll
                for (int v = 0; v < 13; v++)
                    a.psum[chunk * 14 + 1 + v] = v13[v];
            }
        }
    }
    __threadfence();
    grid.sync();

    // ============ Phase 4: merge partials + MLP head (block 0) ============
    if (blockIdx.x == 0) {
        float* sred = smem;                  // [16*13]
        float* tot  = sred + 16 * 13;        // [13]
        float* gv   = tot + 13;              // [12]
        float* h1   = gv + 12;               // [128]
        float* part = h1 + 128;              // [8*128]
        float* h2   = part + 8 * 128;        // [128]
        float* wred = h2 + 128;              // [2*5]
        const int wvid = tid >> 6;           // 0..15

        float m = (tid < nb64) ? a.psum[tid * 14] : -1e30f;
#pragma unroll
        for (int off = 32; off; off >>= 1)
            m = fmaxf(m, __shfl_down(m, off, 64));
        if (lane == 0) sred[wvid] = m;
        __syncthreads();
        float M = sred[0];
#pragma unroll
        for (int i = 1; i < 16; i++) M = fmaxf(M, sred[i]);
        __syncthreads();

        float acc[13];
#pragma unroll
        for (int v = 0; v < 13; v++) acc[v] = 0.f;
        if (tid < nb64) {
            float sc = expf(a.psum[tid * 14] - M);
#pragma unroll
            for (int v = 0; v < 13; v++)
                acc[v] = sc * a.psum[tid * 14 + 1 + v];
        }
#pragma unroll
        for (int v = 0; v < 13; v++) {
            float x = acc[v];
#pragma unroll
            for (int off = 32; off; off >>= 1)
                x += __shfl_down(x, off, 64);
            if (lane == 0) sred[wvid * 13 + v] = x;
        }
        __syncthreads();
        if (tid < 13) {
            float s = 0.f;
#pragma unroll
            for (int i = 0; i < 16; i++) s += sred[i * 13 + tid];
            tot[tid] = s;
        }
        __syncthreads();
        if (tid < DEMB) gv[tid] = tot[1 + tid] / tot[0];
        __syncthreads();

        if (tid < DH) {
            float s1 = a.b1[tid];
#pragma unroll
            for (int i = 0; i < DEMB; i++)
                s1 = fmaf(gv[i], a.W1[i * DH + tid], s1);
            h1[tid] = fmaxf(s1, 0.f);
        }
        __syncthreads();

        {
            const int ks = tid >> 7;         // 0..7
            const int o  = tid & 127;
            float s = 0.f;
            const float* w2 = a.W2 + (size_t)(16 * ks) * DH + o;
#pragma unroll 8
            for (int i = 0; i < 16; i++)
                s = fmaf(h1[16 * ks + i], w2[i * DH], s);
            part[ks * 128 + o] = s;
        }
        __syncthreads();
        if (tid < DH) {
            float s = a.b2[tid];
#pragma unroll
            for (int k = 0; k < 8; k++) s += part[k * 128 + tid];
            h2[tid] = fmaxf(s, 0.f);
        }
        __syncthreads();

        if (tid < DH) {
            const float v = h2[tid];
            float pr[5];
#pragma unroll
            for (int j = 0; j < 4; j++) pr[j] = v * a.Wx[tid * 4 + j];
            pr[4] = v * a.Wy[tid];
#pragma unroll
            for (int j = 0; j < 5; j++) {
                float x = pr[j];
#pragma unroll
                for (int off = 32; off; off >>= 1)
                    x += __shfl_down(x, off, 64);
                if (lane == 0) wred[wvid * 5 + j] = x;
            }
        }
        __syncthreads();
        if (tid < 4)
            a.out[tid] = (wred[tid] + wred[5 + tid] + a.bx[tid]) / 10.0f;
        else if (tid == 4)
            a.out[4] = wred[4] + wred[9] + a.by[0];
    }
}

extern "C" void kernel_launch(void* const* d_in, const int* in_sizes, int n_in,
                              void* d_out, int out_size, void* d_ws, size_t ws_size,
                              hipStream_t stream) {
    const int n_nodes = in_sizes[0] / NF;   // 50000
    const int n_edges = in_sizes[1];        // 1600000
    const int nb64 = (n_nodes + 63) / 64;   // 782

    float* ws = (float*)d_ws;
    KArgs a;
    a.nodes   = (const float*)d_in[0];
    a.senders = (const int*)d_in[1];
    a.recvs   = (const int*)d_in[2];
    a.W_enc = (const float*)d_in[3];  a.b_enc = (const float*)d_in[4];
    a.W_inf = (const float*)d_in[5];  a.b_inf = (const float*)d_in[6];
    a.W_emb = (const float*)d_in[7];  a.b_emb = (const float*)d_in[8];
    a.W1 = (const float*)d_in[9];     a.b1 = (const float*)d_in[10];
    a.W2 = (const float*)d_in[11];    a.b2 = (const float*)d_in[12];
    a.Wy = (const float*)d_in[13];    a.by = (const float*)d_in[14];
    a.Wx = (const float*)d_in[15];    a.bx = (const float*)d_in[16];
    a.p     = ws;                                 // [N]
    a.inflb = ws + n_nodes;                       // [N]
    a.embT  = ws + 2 * (size_t)n_nodes;           // [12][N]
    a.rep2  = ws + 14 * (size_t)n_nodes;          // [nb64][128][64]
    a.psum  = a.rep2 + (size_t)nb64 * ROWB;       // [nb64*14]
    a.out   = (float*)d_out;
    a.n_nodes = n_nodes;
    a.n_edges = n_edges;

    (void)hipFuncSetAttribute((const void*)fused,
                              hipFuncAttributeMaxDynamicSharedMemorySize,
                              R_SCAT * (int)sizeof(float));

    void* kp[] = { (void*)&a };
    (void)hipLaunchCooperativeKernel((void*)fused, dim3(GRID_X), dim3(BLK),
                                     kp, R_SCAT * sizeof(float), stream);
}